// Round 4
// baseline (111.284 us; speedup 1.0000x reference)
//
#include <hip/hip_runtime.h>

// Problem geometry: B=8, H=512, W=512, HID=64, T=16.
#define HH 512
#define WW 512
#define WPR 16                    // u32 words per global row
#define RO 16                     // owned rows per block
#define OW 8                      // owned words per block (256 cols)
#define TW 10                     // tile words = owned + 1 halo word each side
// Halo-word correctness: the dependency cone grows 1 bit/step; with <=8 steps
// per dispatch, corrupted bits of the +/-1 halo word stay >=25 bits away from
// any needed bit (induction over steps) -- safe.

// ---------------------------------------------------------------------------
// Kernel 1: out[0] = f0 (verbatim floats); bit-pack (f0 > 0.5) into field.
// ---------------------------------------------------------------------------
__global__ __launch_bounds__(256) void init_field(const float* __restrict__ f0,
                                                  float* __restrict__ out,
                                                  unsigned long long* __restrict__ field) {
    int c = blockIdx.x * 256 + threadIdx.x;
    float v = f0[c];
    out[c] = v;
    unsigned long long m = __ballot(v > 0.5f);
    if ((threadIdx.x & 63) == 0) field[c >> 6] = m;
}

// ---------------------------------------------------------------------------
// Mega kernel, templated on step count. 512 blocks x 512 threads (2/CU).
// Each block: rule build (exact fp32, verified order) -> pair-LUT ->
// 32x bank-replicated LUT (32 KiB: lane reads its own bank, conflict-free)
// -> load (RO+2*NSTEP)-row x 10-word bit tile -> NSTEP steps, one barrier
// per step, emitting each step's owned 16x256 floats. Optionally writes the
// final bit field for the next dispatch.
// ---------------------------------------------------------------------------
template <int NSTEP, bool EMITF>
__global__ __launch_bounds__(512) void mega(const unsigned int* __restrict__ field,
                                            unsigned int* __restrict__ fieldOut,
                                            const float* __restrict__ W1,
                                            const float* __restrict__ b1,
                                            const float* __restrict__ W2,
                                            const float* __restrict__ b2,
                                            int hid, float* __restrict__ out,
                                            int n, int t0) {
    constexpr int ROWS = RO + 2 * NSTEP;
    __shared__ unsigned int rule[512];
    __shared__ unsigned int lutp[256];
    __shared__ unsigned int lutr[256 * 32];   // 32 KiB bank-replicated
    __shared__ unsigned int bufA[ROWS * TW];
    __shared__ unsigned int bufB[ROWS * TW];

    const int tid = threadIdx.x;
    const int cg = blockIdx.x & 1;
    const int rg = (blockIdx.x >> 1) & 31;
    const int b  = blockIdx.x >> 6;
    const int r0 = rg * RO;          // first owned global row
    const int q0 = cg * OW;          // first owned global word
    const int c0 = cg * (OW * 32);   // first owned global column
    const unsigned int bank = (unsigned int)(tid & 31);

    // (a) rule table -- byte-identical math to the verified build (absmax 0).
    {
        int p = tid;  // 0..511
        float logit = b2[0];
        for (int k = 0; k < hid; ++k) {
            float a = b1[k];
#pragma unroll
            for (int nn = 0; nn < 9; ++nn)
                if (p & (1 << nn)) a += W1[nn * hid + k];
            logit += fmaxf(a, 0.0f) * W2[k];
        }
        rule[p] = (logit > 0.0f) ? 1u : 0u;
    }
    __syncthreads();

    // (b) pair-LUT words: idx12 = u4 | m4<<4 | d4<<8 -> 2 bits (cells c, c+1).
    if (tid < 256) {
        unsigned int wv = 0;
#pragma unroll
        for (int k = 0; k < 16; ++k) {
            unsigned int e = (unsigned int)tid * 16u + k;
            unsigned int u = e & 15u, m = (e >> 4) & 15u, d = (e >> 8) & 15u;
            unsigned int i0 = (u & 7u) | ((m & 7u) << 3) | ((d & 7u) << 6);
            unsigned int i1 = (u >> 1) | ((m >> 1) << 3) | ((d >> 1) << 6);
            wv |= (rule[i0] | (rule[i1] << 1)) << (2 * k);
        }
        lutp[tid] = wv;
    }
    __syncthreads();

    // (c) expand to bank-replicated copy (reads broadcast, writes stride-1)
    //     + load bit tile (wrap in H via &511, in W via &15).
    for (int i = tid; i < 256 * 32; i += 512) lutr[i] = lutp[i >> 5];
    {
        const unsigned int* F = field + b * (HH * WPR);
        for (int i = tid; i < ROWS * TW; i += 512) {
            int l = i / TW, tw = i - l * TW;
            int g  = (r0 - NSTEP + l) & (HH - 1);
            int gw = (q0 - 1 + tw) & (WPR - 1);
            bufA[i] = F[g * WPR + gw];
        }
    }
    __syncthreads();

    unsigned int* oldb = bufA;
    unsigned int* newb = bufB;
    float* outb = out + (size_t)b * (HH * WW);

    for (int s = 1; s <= NSTEP; ++s) {
        // compute: valid new rows [s, ROWS-s); max (ROWS-2)*10 <= 440 < 512.
        const int hi = ROWS - s;
        const int lq = tid / TW;
        const int w  = tid - lq * TW;
        const int l  = s + lq;
        if (l < hi) {
            const unsigned int* Ru = oldb + (l - 1) * TW;
            const unsigned int* Rm = oldb + l * TW;
            const unsigned int* Rd = oldb + (l + 1) * TW;
            const int wl = (w == 0) ? 0 : w - 1;        // garbage-safe (cone)
            const int wn = (w == TW - 1) ? TW - 1 : w + 1;
            unsigned long long eu = ((((unsigned long long)Ru[wn] << 32) | Ru[w]) << 1) | (Ru[wl] >> 31);
            unsigned long long em = ((((unsigned long long)Rm[wn] << 32) | Rm[w]) << 1) | (Rm[wl] >> 31);
            unsigned long long ed = ((((unsigned long long)Rd[wn] << 32) | Rd[w]) << 1) | (Rd[wl] >> 31);
            unsigned int ow = 0;
#pragma unroll
            for (int j = 0; j < 16; ++j) {
                unsigned int idx = (unsigned int)((eu >> (2 * j)) & 15ull)
                                 | ((unsigned int)((em >> (2 * j)) & 15ull) << 4)
                                 | ((unsigned int)((ed >> (2 * j)) & 15ull) << 8);
                unsigned int entry = lutr[((idx >> 4) << 5) | bank];  // own bank
                ow |= ((entry >> ((idx & 15u) * 2)) & 3u) << (2 * j);
            }
            newb[l * TW + w] = ow;
        }
        __syncthreads();   // newb complete; all reads of oldb done.

        // emit step t0+s: owned 16 rows x 256 cols, 2 passes of 512 float4.
        // Overlaps next step's compute (which writes only oldb).
        float* outt = outb + (size_t)(t0 + s) * n;
#pragma unroll
        for (int rep = 0; rep < 2; ++rep) {
            int cell = (rep * 512 + tid) * 4;           // 0..4092, step 4
            int lr  = cell >> 8;                        // owned row 0..15
            int col = cell & 255;                       // owned col
            unsigned int wv = newb[(NSTEP + lr) * TW + 1 + (col >> 5)];
            unsigned int nib = (wv >> (col & 31)) & 15u;
            float4 v;
            v.x = (float)(nib & 1u);
            v.y = (float)((nib >> 1) & 1u);
            v.z = (float)((nib >> 2) & 1u);
            v.w = (float)(nib >> 3);
            *(float4*)(outt + (size_t)(r0 + lr) * WW + c0 + col) = v;
        }
        if (EMITF && s == NSTEP && tid < RO * OW) {
            int row = tid >> 3, w2 = tid & 7;           // owned 16 x 8 words
            fieldOut[b * (HH * WPR) + (r0 + row) * WPR + q0 + w2] =
                newb[(NSTEP + row) * TW + 1 + w2];
        }
        unsigned int* tmp = oldb; oldb = newb; newb = tmp;
    }
}

// ---------------------------------------------------------------------------
// Launch: init_field -> mega<8> (steps 1-8) -> mega<7> (steps 9-15).
// d_ws: [0, 256K) field A (after step 0), [256K, 512K) field B (after step 8).
// ---------------------------------------------------------------------------
extern "C" void kernel_launch(void* const* d_in, const int* in_sizes, int n_in,
                              void* d_out, int out_size, void* d_ws, size_t ws_size,
                              hipStream_t stream) {
    const float* f0 = (const float*)d_in[0];
    const float* W1 = (const float*)d_in[1];
    const float* b1 = (const float*)d_in[2];
    const float* W2 = (const float*)d_in[3];
    const float* b2 = (const float*)d_in[4];
    float* out = (float*)d_out;

    const int n = in_sizes[0];        // B*1*H*W = 2,097,152
    const int hid = in_sizes[2];      // 64
    const int B = n / (HH * WW);      // 8

    char* ws = (char*)d_ws;
    unsigned long long* fldA = (unsigned long long*)ws;
    unsigned int* fldB = (unsigned int*)(ws + (size_t)(n / 8));

    init_field<<<n / 256, 256, 0, stream>>>(f0, out, fldA);
    mega<8, true><<<B * (HH / RO) * 2, 512, 0, stream>>>(
        (const unsigned int*)fldA, fldB, W1, b1, W2, b2, hid, out, n, 0);
    mega<7, false><<<B * (HH / RO) * 2, 512, 0, stream>>>(
        (const unsigned int*)fldB, nullptr, W1, b1, W2, b2, hid, out, n, 8);
}

// Round 6
// 87.812 us; speedup vs baseline: 1.2673x; 1.2673x over previous
//
#include <hip/hip_runtime.h>

// Problem geometry: B=8, H=512, W=512, HID=64, T=16.
#define HH 512
#define WW 512
#define WPR 16                    // u32 words per global row
#define RO 16                     // owned rows per block
#define NSTEP 15                  // temporal blocking depth (T-1)
#define ROWS (RO + 2 * NSTEP)     // 46 tile rows
#define OW 8                      // owned words per block (256 cols)
#define TW 10                     // tile words = owned + 1 halo word each side
#define TCOLS (TW * 32)           // 320 tile cols
// Halo-word correctness: the dependency cone grows 1 bit/step; needed bits of
// the +/-1 halo word at step s stay clear of corrupted bits (<= s-1) for all
// 15 steps (induction) -- verified absmax 0.0 in rounds 2-4.

// ---------------------------------------------------------------------------
// Single mega kernel. 512 blocks (8 images x 32 row-groups x 2 col-groups)
// x 512 threads. Phases:
//  (a) 512-entry rule build (exact fp32, same add order as reference einsum —
//      verified absmax 0.0 in rounds 1-4) + 4096-entry pair-LUT (1 KiB).
//  (b) pack f0 tile (46 rows x 320 cols) into bufA via wave-aligned ballots;
//      owned cells also copy f0 verbatim to out[0].
//  (c) 15 steps, ONE lgkm-only barrier each: NO global stores inside the
//      loop; owned bits of each step land in obits (7.5 KiB LDS).
//  (d) barrier-free streaming emit: 30 x 512 float4 stores (1 KiB contiguous
//      per wave) expand obits -> frames 1..15.
// ---------------------------------------------------------------------------
__global__ __launch_bounds__(512) void mega(const float* __restrict__ f0,
                                            const float* __restrict__ W1,
                                            const float* __restrict__ b1,
                                            const float* __restrict__ W2,
                                            const float* __restrict__ b2,
                                            int hid, float* __restrict__ out,
                                            int n) {
    __shared__ unsigned int rule[512];
    __shared__ unsigned int lutp[256];
    __shared__ unsigned int bufA[ROWS * TW];
    __shared__ unsigned int bufB[ROWS * TW];
    __shared__ unsigned int obits[NSTEP * RO * OW];   // 15*128 words = 7.5 KiB

    const int tid = threadIdx.x;
    const int cg = blockIdx.x & 1;
    const int rg = (blockIdx.x >> 1) & 31;
    const int b  = blockIdx.x >> 6;
    const int r0 = rg * RO;          // first owned global row
    const int q0 = cg * OW;          // first owned global word (unused, doc)
    const int c0 = cg * (OW * 32);   // first owned global column
    (void)q0;

    // (a) rule table — byte-identical math to the verified build.
    {
        int p = tid;  // 0..511
        float logit = b2[0];
        for (int k = 0; k < hid; ++k) {
            float a = b1[k];
#pragma unroll
            for (int nn = 0; nn < 9; ++nn)
                if (p & (1 << nn)) a += W1[nn * hid + k];
            logit += fmaxf(a, 0.0f) * W2[k];
        }
        rule[p] = (logit > 0.0f) ? 1u : 0u;
    }
    __syncthreads();

    // pair-LUT: idx12 = u4 | m4<<4 | d4<<8 -> 2 bits (cells c, c+1).
    if (tid < 256) {
        unsigned int wv = 0;
#pragma unroll
        for (int k = 0; k < 16; ++k) {
            unsigned int e = (unsigned int)tid * 16u + k;
            unsigned int u = e & 15u, m = (e >> 4) & 15u, d = (e >> 8) & 15u;
            unsigned int i0 = (u & 7u) | ((m & 7u) << 3) | ((d & 7u) << 6);
            unsigned int i1 = (u >> 1) | ((m >> 1) << 3) | ((d >> 1) << 6);
            wv |= (rule[i0] | (rule[i1] << 1)) << (2 * k);
        }
        lutp[tid] = wv;
    }

    // (b) pack f0 tile + frame-0 verbatim copy for owned cells.
    // 46*320 = 14720 cells; stride 512: chunk starts are 64-aligned and
    // 320 = 5*64, so each wave's 64 cells sit inside one row at a 64-aligned
    // column base. Last pass activates exactly 6 full waves (384 threads), so
    // every executed __ballot has its full wave present.
    // Ballot bit `lane` = column (c_base + lane): lane 0's word is c>>5,
    // lane 32's own c>>5 is ALREADY the next word (round-5 bug was a +1 here).
    {
        const float* f0b = f0 + (size_t)b * (HH * WW);
        float* out0 = out + (size_t)b * (HH * WW);
        for (int i = tid; i < ROWS * TCOLS; i += 512) {
            int l = i / TCOLS, c = i - l * TCOLS;
            int gr = (r0 - NSTEP + l) & (HH - 1);
            int gc = (c0 - 32 + c) & (WW - 1);
            float v = f0b[(size_t)gr * WW + gc];
            unsigned long long m = __ballot(v > 0.5f);
            int lane = tid & 63;
            if (lane == 0)  bufA[l * TW + (c >> 5)] = (unsigned int)m;
            if (lane == 32) bufA[l * TW + (c >> 5)] = (unsigned int)(m >> 32);
            // owned region: rows [NSTEP, NSTEP+RO), cols [32, 32+256)
            if (l >= NSTEP && l < NSTEP + RO && c >= 32 && c < 32 + 256)
                out0[(size_t)gr * WW + gc] = v;
        }
    }
    __syncthreads();

    unsigned int* oldb = bufA;
    unsigned int* newb = bufB;

    // (c) 15 steps, no global traffic inside the loop.
    for (int s = 1; s <= NSTEP; ++s) {
        const int hi = ROWS - s;         // valid new rows [s, hi)
        const int lq = tid / TW;
        const int w  = tid - lq * TW;
        const int l  = s + lq;
        if (l < hi) {                     // max 44*10 = 440 < 512 threads
            const unsigned int* Ru = oldb + (l - 1) * TW;
            const unsigned int* Rm = oldb + l * TW;
            const unsigned int* Rd = oldb + (l + 1) * TW;
            const int wl = (w == 0) ? 0 : w - 1;        // garbage-safe (cone)
            const int wn = (w == TW - 1) ? TW - 1 : w + 1;
            unsigned long long eu = ((((unsigned long long)Ru[wn] << 32) | Ru[w]) << 1) | (Ru[wl] >> 31);
            unsigned long long em = ((((unsigned long long)Rm[wn] << 32) | Rm[w]) << 1) | (Rm[wl] >> 31);
            unsigned long long ed = ((((unsigned long long)Rd[wn] << 32) | Rd[w]) << 1) | (Rd[wl] >> 31);
            unsigned int ow = 0;
#pragma unroll
            for (int j = 0; j < 16; ++j) {
                unsigned int idx = (unsigned int)((eu >> (2 * j)) & 15ull)
                                 | ((unsigned int)((em >> (2 * j)) & 15ull) << 4)
                                 | ((unsigned int)((ed >> (2 * j)) & 15ull) << 8);
                ow |= ((lutp[idx >> 4] >> ((idx & 15u) * 2)) & 3u) << (2 * j);
            }
            newb[l * TW + w] = ow;
            if (l >= NSTEP && l < NSTEP + RO && w >= 1 && w <= OW)
                obits[(s - 1) * (RO * OW) + (l - NSTEP) * OW + (w - 1)] = ow;
        }
        __syncthreads();
        unsigned int* tmp = oldb; oldb = newb; newb = tmp;
    }

    // (d) streaming emit of frames 1..15: 15*4096 floats per block,
    // 30 passes x 512 threads x float4; each wave writes 1 KiB contiguous.
    {
        float* outb = out + (size_t)b * (HH * WW);
#pragma unroll 2
        for (int rep = 0; rep < 2 * NSTEP; ++rep) {
            int idx4 = (rep * 512 + tid) * 4;          // cell*4 index
            int s   = idx4 >> 12;                      // step-1 (0..14)
            int cell = idx4 & 4095;
            int lr  = cell >> 8;                       // owned row 0..15
            int col = cell & 255;                      // owned col 0..255
            unsigned int wv = obits[s * (RO * OW) + lr * OW + (col >> 5)];
            unsigned int nib = (wv >> (col & 31)) & 15u;
            float4 v;
            v.x = (float)(nib & 1u);
            v.y = (float)((nib >> 1) & 1u);
            v.z = (float)((nib >> 2) & 1u);
            v.w = (float)(nib >> 3);
            *(float4*)(outb + (size_t)(s + 1) * n + (size_t)(r0 + lr) * WW + c0 + col) = v;
        }
    }
}

// ---------------------------------------------------------------------------
// Launch: ONE dispatch. No workspace needed.
// ---------------------------------------------------------------------------
extern "C" void kernel_launch(void* const* d_in, const int* in_sizes, int n_in,
                              void* d_out, int out_size, void* d_ws, size_t ws_size,
                              hipStream_t stream) {
    const float* f0 = (const float*)d_in[0];
    const float* W1 = (const float*)d_in[1];
    const float* b1 = (const float*)d_in[2];
    const float* W2 = (const float*)d_in[3];
    const float* b2 = (const float*)d_in[4];
    float* out = (float*)d_out;

    const int n = in_sizes[0];        // B*1*H*W = 2,097,152
    const int hid = in_sizes[2];      // 64
    const int B = n / (HH * WW);      // 8

    mega<<<B * (HH / RO) * 2, 512, 0, stream>>>(f0, W1, b1, W2, b2, hid, out, n);
}

// Round 7
// 66.513 us; speedup vs baseline: 1.6731x; 1.3202x over previous
//
#include <hip/hip_runtime.h>

// Problem geometry: B=8, H=512, W=512, HID=64, T=16.
#define HH 512
#define WW 512
#define WPR 16                    // u32 words per global row
#define RO 16                     // owned rows per block
#define HALO 15                   // T-1 steps of temporal blocking
#define ROWS (RO + 2 * HALO)      // 46 rows staged in LDS
#define OW 8                      // owned words per block (256 cols)
#define TW 10                     // tile words = owned + 1 halo word each side
// Halo-word correctness: the dependency cone grows 1 bit/step; needed bits of
// the +/-1 halo word at step s stay clear of corrupted bits (<= s-1) for all
// 15 steps (induction) -- verified absmax 0.0 in rounds 2,3,4,6.

// lgkm-only barrier: unlike __syncthreads() (which the compiler lowers with a
// full s_waitcnt vmcnt(0) drain), this waits only on LDS ops, letting the
// per-step global float stores stay in flight across steps (T3/T4 idiom).
#define STEP_BARRIER() do {                                   \
    asm volatile("s_waitcnt lgkmcnt(0)" ::: "memory");        \
    __builtin_amdgcn_s_barrier();                             \
    __builtin_amdgcn_sched_barrier(0);                        \
} while (0)

// ---------------------------------------------------------------------------
// Kernel 1: out[0] = f0 (verbatim floats); bit-pack (f0 > 0.5) into field.
// (verified bit-exact in rounds 2-4)
// ---------------------------------------------------------------------------
__global__ __launch_bounds__(256) void init_field(const float* __restrict__ f0,
                                                  float* __restrict__ out,
                                                  unsigned long long* __restrict__ field) {
    int c = blockIdx.x * 256 + threadIdx.x;
    float v = f0[c];
    out[c] = v;
    unsigned long long m = __ballot(v > 0.5f);
    if ((threadIdx.x & 63) == 0) field[c >> 6] = m;
}

// ---------------------------------------------------------------------------
// Kernel 2: rule build + pair-LUT + tile load + 15 steps with in-loop float
// emission. 512 blocks (8 images x 32 row-groups x 2 col-groups) x 512
// threads = 2 blocks/CU. ONE lgkm-only barrier per step; frame stores of step
// s stream while step s+1 computes.
// ---------------------------------------------------------------------------
__global__ __launch_bounds__(512) void mega(const unsigned int* __restrict__ field,
                                            const float* __restrict__ W1,
                                            const float* __restrict__ b1,
                                            const float* __restrict__ W2,
                                            const float* __restrict__ b2,
                                            int hid, float* __restrict__ out,
                                            int n, int T) {
    __shared__ unsigned int rule[512];
    __shared__ unsigned int lutp[256];
    __shared__ unsigned int bufA[ROWS * TW];
    __shared__ unsigned int bufB[ROWS * TW];

    const int tid = threadIdx.x;
    const int cg = blockIdx.x & 1;
    const int rg = (blockIdx.x >> 1) & 31;
    const int b  = blockIdx.x >> 6;
    const int r0 = rg * RO;          // first owned global row
    const int q0 = cg * OW;          // first owned global word
    const int c0 = cg * (OW * 32);   // first owned global column

    // (a) rule table — byte-identical math to the verified build (absmax 0).
    {
        int p = tid;  // 0..511
        float logit = b2[0];
        for (int k = 0; k < hid; ++k) {
            float a = b1[k];
#pragma unroll
            for (int nn = 0; nn < 9; ++nn)
                if (p & (1 << nn)) a += W1[nn * hid + k];
            logit += fmaxf(a, 0.0f) * W2[k];
        }
        rule[p] = (logit > 0.0f) ? 1u : 0u;
    }
    __syncthreads();

    // (b) pair-LUT: idx12 = u4 | m4<<4 | d4<<8 -> 2 bits (cells c, c+1).
    if (tid < 256) {
        unsigned int wv = 0;
#pragma unroll
        for (int k = 0; k < 16; ++k) {
            unsigned int e = (unsigned int)tid * 16u + k;
            unsigned int u = e & 15u, m = (e >> 4) & 15u, d = (e >> 8) & 15u;
            unsigned int i0 = (u & 7u) | ((m & 7u) << 3) | ((d & 7u) << 6);
            unsigned int i1 = (u >> 1) | ((m >> 1) << 3) | ((d >> 1) << 6);
            wv |= (rule[i0] | (rule[i1] << 1)) << (2 * k);
        }
        lutp[tid] = wv;
    }

    // (c) load bit tile (wrap in H via &511, in W via &15).
    {
        const unsigned int* F = field + b * (HH * WPR);
        for (int i = tid; i < ROWS * TW; i += 512) {
            int l = i / TW, tw = i - l * TW;
            int g  = (r0 - HALO + l) & (HH - 1);
            int gw = (q0 - 1 + tw) & (WPR - 1);
            bufA[i] = F[g * WPR + gw];
        }
    }
    __syncthreads();

    unsigned int* oldb = bufA;
    unsigned int* newb = bufB;
    float* outb = out + (size_t)b * (HH * WW);

    for (int t = 1; t < T; ++t) {
        // compute: valid new rows [t, ROWS-t); max 44*10 = 440 < 512 threads.
        const int hi = ROWS - t;
        const int lq = tid / TW;
        const int w  = tid - lq * TW;
        const int l  = t + lq;
        if (l < hi) {
            const unsigned int* Ru = oldb + (l - 1) * TW;
            const unsigned int* Rm = oldb + l * TW;
            const unsigned int* Rd = oldb + (l + 1) * TW;
            const int wl = (w == 0) ? 0 : w - 1;        // garbage-safe (cone)
            const int wn = (w == TW - 1) ? TW - 1 : w + 1;
            unsigned long long eu = ((((unsigned long long)Ru[wn] << 32) | Ru[w]) << 1) | (Ru[wl] >> 31);
            unsigned long long em = ((((unsigned long long)Rm[wn] << 32) | Rm[w]) << 1) | (Rm[wl] >> 31);
            unsigned long long ed = ((((unsigned long long)Rd[wn] << 32) | Rd[w]) << 1) | (Rd[wl] >> 31);
            unsigned int ow = 0;
#pragma unroll
            for (int j = 0; j < 16; ++j) {
                unsigned int idx = (unsigned int)((eu >> (2 * j)) & 15ull)
                                 | ((unsigned int)((em >> (2 * j)) & 15ull) << 4)
                                 | ((unsigned int)((ed >> (2 * j)) & 15ull) << 8);
                ow |= ((lutp[idx >> 4] >> ((idx & 15u) * 2)) & 3u) << (2 * j);
            }
            newb[l * TW + w] = ow;
        }
        STEP_BARRIER();    // lgkm-only: newb complete, oldb reads done;
                           // frame stores from previous steps stay in flight.

        // emit step t: owned 16 rows x 256 cols, 2 passes of 512 float4.
        // Overlaps next step's compute (which writes only oldb); these ds_reads
        // complete by the NEXT barrier, one full step before newb is reused.
        float* outt = outb + (size_t)t * n;
#pragma unroll
        for (int rep = 0; rep < 2; ++rep) {
            int cell = (rep * 512 + tid) * 4;           // 0..4092, step 4
            int lr  = cell >> 8;                        // owned row 0..15
            int col = cell & 255;                       // owned col
            unsigned int wv = newb[(HALO + lr) * TW + 1 + (col >> 5)];
            unsigned int nib = (wv >> (col & 31)) & 15u;
            float4 v;
            v.x = (float)(nib & 1u);
            v.y = (float)((nib >> 1) & 1u);
            v.z = (float)((nib >> 2) & 1u);
            v.w = (float)(nib >> 3);
            *(float4*)(outt + (size_t)(r0 + lr) * WW + c0 + col) = v;
        }
        unsigned int* tmp = oldb; oldb = newb; newb = tmp;
    }
}

// ---------------------------------------------------------------------------
// Launch: init_field -> mega (2 dispatches).
// d_ws: [0, n/8) packed step-0 bit field (256 KiB).
// ---------------------------------------------------------------------------
extern "C" void kernel_launch(void* const* d_in, const int* in_sizes, int n_in,
                              void* d_out, int out_size, void* d_ws, size_t ws_size,
                              hipStream_t stream) {
    const float* f0 = (const float*)d_in[0];
    const float* W1 = (const float*)d_in[1];
    const float* b1 = (const float*)d_in[2];
    const float* W2 = (const float*)d_in[3];
    const float* b2 = (const float*)d_in[4];
    float* out = (float*)d_out;

    const int n = in_sizes[0];        // B*1*H*W = 2,097,152
    const int hid = in_sizes[2];      // 64
    const int T = out_size / n;       // 16
    const int B = n / (HH * WW);      // 8

    unsigned long long* fld = (unsigned long long*)d_ws;

    init_field<<<n / 256, 256, 0, stream>>>(f0, out, fld);
    mega<<<B * (HH / RO) * 2, 512, 0, stream>>>((const unsigned int*)fld,
                                                W1, b1, W2, b2, hid, out, n, T);
}

// Round 8
// 63.357 us; speedup vs baseline: 1.7565x; 1.0498x over previous
//
#include <hip/hip_runtime.h>

// Problem geometry: B=8, H=512, W=512, HID=64, T=16.
#define HH 512
#define WW 512
#define WPR 16                    // u32 words per global row
#define RO 8                      // owned rows per block (was 16; grid x2)
#define HALO 15                   // T-1 steps of temporal blocking
#define ROWS (RO + 2 * HALO)      // 38 rows staged in LDS
#define OW 8                      // owned words per block (256 cols)
#define TW 10                     // tile words = owned + 1 halo word each side
// Halo-word correctness: the dependency cone grows 1 bit/step; needed bits of
// the +/-1 halo word at step s stay clear of corrupted bits (<= s-1) for all
// 15 steps (induction) -- verified absmax 0.0 in rounds 2,3,4,6,7.

// lgkm-only barrier (verified round 7): waits only on LDS ops, letting the
// per-step global float stores stay in flight across steps.
#define STEP_BARRIER() do {                                   \
    asm volatile("s_waitcnt lgkmcnt(0)" ::: "memory");        \
    __builtin_amdgcn_s_barrier();                             \
    __builtin_amdgcn_sched_barrier(0);                        \
} while (0)

// ---------------------------------------------------------------------------
// Kernel 1: out[0] = f0 (verbatim); bit-pack (f0>0.5) into field. Block 0
// ADDITIONALLY builds the 512-entry rule + 4096-entry pair-LUT into d_ws
// (overlapped with the other 4095 blocks' packing; removes the serial
// rule-build preamble from every mega block).
// ---------------------------------------------------------------------------
__global__ __launch_bounds__(512) void init_pack(const float* __restrict__ f0,
                                                 const float* __restrict__ W1,
                                                 const float* __restrict__ b1,
                                                 const float* __restrict__ W2,
                                                 const float* __restrict__ b2,
                                                 int hid,
                                                 float* __restrict__ out,
                                                 unsigned long long* __restrict__ field,
                                                 unsigned int* __restrict__ lutg) {
    __shared__ unsigned int rule[512];
    const int tid = threadIdx.x;
    int c = blockIdx.x * 512 + tid;
    float v = f0[c];
    out[c] = v;
    unsigned long long m = __ballot(v > 0.5f);
    if ((tid & 63) == 0) field[c >> 6] = m;

    if (blockIdx.x == 0) {
        // rule table — byte-identical math to the verified build (absmax 0).
        {
            int p = tid;  // 0..511
            float logit = b2[0];
            for (int k = 0; k < hid; ++k) {
                float a = b1[k];
#pragma unroll
                for (int nn = 0; nn < 9; ++nn)
                    if (p & (1 << nn)) a += W1[nn * hid + k];
                logit += fmaxf(a, 0.0f) * W2[k];
            }
            rule[p] = (logit > 0.0f) ? 1u : 0u;
        }
        __syncthreads();
        // pair-LUT: idx12 = u4 | m4<<4 | d4<<8 -> 2 bits (cells c, c+1).
        if (tid < 256) {
            unsigned int wv = 0;
#pragma unroll
            for (int k = 0; k < 16; ++k) {
                unsigned int e = (unsigned int)tid * 16u + k;
                unsigned int u = e & 15u, mm = (e >> 4) & 15u, d = (e >> 8) & 15u;
                unsigned int i0 = (u & 7u) | ((mm & 7u) << 3) | ((d & 7u) << 6);
                unsigned int i1 = (u >> 1) | ((mm >> 1) << 3) | ((d >> 1) << 6);
                wv |= (rule[i0] | (rule[i1] << 1)) << (2 * k);
            }
            lutg[tid] = wv;
        }
    }
}

// ---------------------------------------------------------------------------
// Kernel 2: 1024 blocks (8 images x 64 row-groups x 2 col-groups) x 512
// threads = 4 blocks/CU = 32 waves/CU (max occupancy). Preamble: 1 KiB LUT
// load + 38x10-word tile load. 15 steps, one lgkm-only barrier each, in-loop
// float4 emission (1 store/thread/step) streaming while the next step computes.
// ---------------------------------------------------------------------------
__global__ __launch_bounds__(512) void mega(const unsigned int* __restrict__ field,
                                            const unsigned int* __restrict__ lutg,
                                            float* __restrict__ out,
                                            int n, int T) {
    __shared__ unsigned int lutp[256];
    __shared__ unsigned int bufA[ROWS * TW];
    __shared__ unsigned int bufB[ROWS * TW];

    const int tid = threadIdx.x;
    const int cg = blockIdx.x & 1;
    const int rg = (blockIdx.x >> 1) & 63;
    const int b  = blockIdx.x >> 7;
    const int r0 = rg * RO;          // first owned global row
    const int q0 = cg * OW;          // first owned global word
    const int c0 = cg * (OW * 32);   // first owned global column

    if (tid < 256) lutp[tid] = lutg[tid];
    {
        const unsigned int* F = field + b * (HH * WPR);
        for (int i = tid; i < ROWS * TW; i += 512) {
            int l = i / TW, tw = i - l * TW;
            int g  = (r0 - HALO + l) & (HH - 1);
            int gw = (q0 - 1 + tw) & (WPR - 1);
            bufA[i] = F[g * WPR + gw];
        }
    }
    __syncthreads();

    unsigned int* oldb = bufA;
    unsigned int* newb = bufB;
    float* outb = out + (size_t)b * (HH * WW);

    for (int t = 1; t < T; ++t) {
        // compute: valid new rows [t, ROWS-t); max 36*10 = 360 < 512 threads.
        const int hi = ROWS - t;
        const int lq = tid / TW;
        const int w  = tid - lq * TW;
        const int l  = t + lq;
        if (l < hi) {
            const unsigned int* Ru = oldb + (l - 1) * TW;
            const unsigned int* Rm = oldb + l * TW;
            const unsigned int* Rd = oldb + (l + 1) * TW;
            const int wl = (w == 0) ? 0 : w - 1;        // garbage-safe (cone)
            const int wn = (w == TW - 1) ? TW - 1 : w + 1;
            unsigned long long eu = ((((unsigned long long)Ru[wn] << 32) | Ru[w]) << 1) | (Ru[wl] >> 31);
            unsigned long long em = ((((unsigned long long)Rm[wn] << 32) | Rm[w]) << 1) | (Rm[wl] >> 31);
            unsigned long long ed = ((((unsigned long long)Rd[wn] << 32) | Rd[w]) << 1) | (Rd[wl] >> 31);
            unsigned int ow = 0;
#pragma unroll
            for (int j = 0; j < 16; ++j) {
                unsigned int idx = (unsigned int)((eu >> (2 * j)) & 15ull)
                                 | ((unsigned int)((em >> (2 * j)) & 15ull) << 4)
                                 | ((unsigned int)((ed >> (2 * j)) & 15ull) << 8);
                ow |= ((lutp[idx >> 4] >> ((idx & 15u) * 2)) & 3u) << (2 * j);
            }
            newb[l * TW + w] = ow;
        }
        STEP_BARRIER();    // lgkm-only: newb complete, oldb reads done;
                           // frame stores from previous steps stay in flight.

        // emit step t: owned 8 rows x 256 cols = 2048 floats = 512 float4
        // (exactly one per thread). Overlaps next step's compute (writes oldb
        // only); these ds_reads complete by the NEXT barrier, one full step
        // before newb is reused.
        float* outt = outb + (size_t)t * n;
        {
            int cell = tid * 4;                        // 0..2044, step 4
            int lr  = cell >> 8;                       // owned row 0..7
            int col = cell & 255;                      // owned col
            unsigned int wv = newb[(HALO + lr) * TW + 1 + (col >> 5)];
            unsigned int nib = (wv >> (col & 31)) & 15u;
            float4 v;
            v.x = (float)(nib & 1u);
            v.y = (float)((nib >> 1) & 1u);
            v.z = (float)((nib >> 2) & 1u);
            v.w = (float)(nib >> 3);
            *(float4*)(outt + (size_t)(r0 + lr) * WW + c0 + col) = v;
        }
        unsigned int* tmp = oldb; oldb = newb; newb = tmp;
    }
}

// ---------------------------------------------------------------------------
// Launch: init_pack -> mega (2 dispatches).
// d_ws: [0, 1024)           pair-LUT (256 u32)
//       [1024, 1024 + n/8)  packed step-0 bit field (256 KiB)
// ---------------------------------------------------------------------------
extern "C" void kernel_launch(void* const* d_in, const int* in_sizes, int n_in,
                              void* d_out, int out_size, void* d_ws, size_t ws_size,
                              hipStream_t stream) {
    const float* f0 = (const float*)d_in[0];
    const float* W1 = (const float*)d_in[1];
    const float* b1 = (const float*)d_in[2];
    const float* W2 = (const float*)d_in[3];
    const float* b2 = (const float*)d_in[4];
    float* out = (float*)d_out;

    const int n = in_sizes[0];        // B*1*H*W = 2,097,152
    const int hid = in_sizes[2];      // 64
    const int T = out_size / n;       // 16
    const int B = n / (HH * WW);      // 8

    char* ws = (char*)d_ws;
    unsigned int* lutg = (unsigned int*)ws;
    unsigned long long* fld = (unsigned long long*)(ws + 1024);

    init_pack<<<n / 512, 512, 0, stream>>>(f0, W1, b1, W2, b2, hid, out, fld, lutg);
    mega<<<B * (HH / RO) * 2, 512, 0, stream>>>((const unsigned int*)fld, lutg,
                                                out, n, T);
}